// Round 2
// baseline (265.865 us; speedup 1.0000x reference)
//
#include <hip/hip_runtime.h>

#define B_   256
#define J_   140
#define VN_  14000
#define NKP  22
#define NB   4

#define OFF_J (B_ * VN_ * 3)                 // start of J_final in d_out
#define OFF_K (OFF_J + B_ * J_ * 3)          // start of keypoints in d_out

// ---------------------------------------------------------------------------
// Kernel 1: per-batch kinematic chain.
// One block (= one wave, 64 threads) per batch. Level-parallel composition.
// All loops are statically bounded; parents are clamped so every chase
// strictly descends. Handles parents delivered as int32 OR int64.
// ---------------------------------------------------------------------------
__global__ __launch_bounds__(64) void chain_kernel(
    const float* __restrict__ rotvec,   // (B,J,3)
    const float* __restrict__ ptrans,   // (B,J,3)
    const float* __restrict__ tpose,    // (J,3)
    const void*  __restrict__ parents_raw, // (J,) int32 or int64
    float* __restrict__ Aout,           // ws: (B,J,12)
    float* __restrict__ Jout)           // out+OFF_J: (B,J,3)
{
    __shared__ float sS[J_][12];
    __shared__ float sG[J_][12];
    __shared__ int   sPar[J_];
    __shared__ int   sLev[J_];
    __shared__ int   sMax;

    const int b = blockIdx.x;
    const int t = threadIdx.x;

    // --- detect parents dtype: int64 viewed as int32 has all-zero odd words
    const int* p32 = (const int*)parents_raw;
    bool is64 = true;
    for (int k = 0; k < J_ / 2; ++k) {          // bounded, reads <= 560B
        if (p32[2 * k + 1] != 0) { is64 = false; break; }
    }

    // --- Rodrigues + local transforms S, and clamped parents
    for (int j = t; j < J_; j += 64) {
        int p = is64 ? p32[2 * j] : p32[j];
        if (j == 0 || p < 0 || p >= j) p = 0;   // guarantees strict descent
        sPar[j] = p;

        const size_t base = ((size_t)b * J_ + j) * 3;
        const float rx = rotvec[base + 0];
        const float ry = rotvec[base + 1];
        const float rz = rotvec[base + 2];
        const float th  = sqrtf(rx * rx + ry * ry + rz * rz) + 1e-8f;
        const float inv = 1.0f / th;
        const float ux = rx * inv, uy = ry * inv, uz = rz * inv;
        const float c = cosf(th), s = sinf(th);
        const float omc = 1.0f - c;

        sS[j][0]  = c + omc * ux * ux;
        sS[j][1]  = omc * ux * uy - s * uz;
        sS[j][2]  = omc * ux * uz + s * uy;
        sS[j][4]  = omc * uy * ux + s * uz;
        sS[j][5]  = c + omc * uy * uy;
        sS[j][6]  = omc * uy * uz - s * ux;
        sS[j][8]  = omc * uz * ux - s * uy;
        sS[j][9]  = omc * uz * uy + s * ux;
        sS[j][10] = c + omc * uz * uz;
        sS[j][3]  = ptrans[base + 0];
        sS[j][7]  = ptrans[base + 1];
        sS[j][11] = ptrans[base + 2];
    }
    __syncthreads();

    // --- depth of each joint: bounded chase on clamped parents
    int lmax = 0;
    for (int j = t; j < J_; j += 64) {
        int d = 0, k = j;
        for (int it = 0; it < J_ && k != 0; ++it) { k = sPar[k]; ++d; }
        sLev[j] = d;
        lmax = max(lmax, d);
        if (d == 0) {
            #pragma unroll
            for (int q = 0; q < 12; ++q) sG[j][q] = sS[j][q];
        }
    }
    #pragma unroll
    for (int off = 32; off > 0; off >>= 1)      // block == 1 wave
        lmax = max(lmax, __shfl_xor(lmax, off));
    if (t == 0) sMax = lmax;
    __syncthreads();

    // --- level-parallel composition G[j] = G[par] @ S[j]
    const int maxd = sMax;
    for (int L = 1; L <= maxd; ++L) {
        for (int j = t; j < J_; j += 64) {
            if (sLev[j] == L) {
                const int p = sPar[j];
                float g[12];
                #pragma unroll
                for (int m = 0; m < 3; ++m) {
                    const float a0 = sG[p][m * 4 + 0];
                    const float a1 = sG[p][m * 4 + 1];
                    const float a2 = sG[p][m * 4 + 2];
                    const float a3 = sG[p][m * 4 + 3];
                    g[m * 4 + 0] = a0 * sS[j][0] + a1 * sS[j][4] + a2 * sS[j][8];
                    g[m * 4 + 1] = a0 * sS[j][1] + a1 * sS[j][5] + a2 * sS[j][9];
                    g[m * 4 + 2] = a0 * sS[j][2] + a1 * sS[j][6] + a2 * sS[j][10];
                    g[m * 4 + 3] = a0 * sS[j][3] + a1 * sS[j][7] + a2 * sS[j][11] + a3;
                }
                #pragma unroll
                for (int q = 0; q < 12; ++q) sG[j][q] = g[q];
            }
        }
        __syncthreads();
    }

    // --- A = [G_R | G_t - G_R * tpose]; J_final = G_t
    for (int j = t; j < J_; j += 64) {
        const float tx = tpose[j * 3 + 0];
        const float ty = tpose[j * 3 + 1];
        const float tz = tpose[j * 3 + 2];
        float* Ar = Aout + ((size_t)b * J_ + j) * 12;
        #pragma unroll
        for (int m = 0; m < 3; ++m) {
            const float r0 = sG[j][m * 4 + 0];
            const float r1 = sG[j][m * 4 + 1];
            const float r2 = sG[j][m * 4 + 2];
            const float gt = sG[j][m * 4 + 3];
            Ar[m * 4 + 0] = r0;
            Ar[m * 4 + 1] = r1;
            Ar[m * 4 + 2] = r2;
            Ar[m * 4 + 3] = gt - (r0 * tx + r1 * ty + r2 * tz);
            Jout[((size_t)b * J_ + j) * 3 + m] = gt;
        }
    }
}

// ---------------------------------------------------------------------------
// Kernel 2: LBS. One vertex per thread, NB=4 batches per block.
// A indices are wave-uniform -> scalar (SGPR) loads; w is per-lane float4.
// Pure-VALU inner loop: 48 FMA per joint per thread.
// ---------------------------------------------------------------------------
__global__ __launch_bounds__(256) void lbs_kernel(
    const float* __restrict__ vt,   // (VN,3)
    const float* __restrict__ w,    // (VN,J)
    const float* __restrict__ Aw,   // ws: (B,J,12)
    float* __restrict__ out)        // (B,VN,3)
{
    const int v = blockIdx.x * 256 + threadIdx.x;
    if (v >= VN_) return;
    const int b0 = blockIdx.y * NB;

    float acc[NB][12];
    #pragma unroll
    for (int bt = 0; bt < NB; ++bt)
        #pragma unroll
        for (int k = 0; k < 12; ++k) acc[bt][k] = 0.0f;

    const float* wrow = w + (size_t)v * J_;

    for (int j = 0; j < J_; j += 4) {   // 140 % 4 == 0
        const float4 wv = *(const float4*)(wrow + j);
        const float wj[4] = { wv.x, wv.y, wv.z, wv.w };
        #pragma unroll
        for (int jj = 0; jj < 4; ++jj) {
            const float wcur = wj[jj];
            #pragma unroll
            for (int bt = 0; bt < NB; ++bt) {
                const float* Aj = Aw + ((size_t)(b0 + bt) * J_ + (j + jj)) * 12;
                #pragma unroll
                for (int k = 0; k < 12; ++k)
                    acc[bt][k] = fmaf(wcur, Aj[k], acc[bt][k]);
            }
        }
    }

    const float x = vt[v * 3 + 0];
    const float y = vt[v * 3 + 1];
    const float z = vt[v * 3 + 2];
    #pragma unroll
    for (int bt = 0; bt < NB; ++bt) {
        float* o = out + ((size_t)(b0 + bt) * VN_ + v) * 3;
        o[0] = acc[bt][0] * x + acc[bt][1] * y + acc[bt][2]  * z + acc[bt][3];
        o[1] = acc[bt][4] * x + acc[bt][5] * y + acc[bt][6]  * z + acc[bt][7];
        o[2] = acc[bt][8] * x + acc[bt][9] * y + acc[bt][10] * z + acc[bt][11];
    }
}

// ---------------------------------------------------------------------------
// Kernel 3: keypoints. Reads V_final / J_final already in d_out.
// ---------------------------------------------------------------------------
__global__ __launch_bounds__(256) void kp_kernel(
    const int* __restrict__ kpv,    // (22,4) int32
    const int* __restrict__ kpj,    // (22,2) int32
    const int* __restrict__ kpb,    // (22,)  bool delivered as int32
    float* __restrict__ out)
{
    const int i = blockIdx.x * 256 + threadIdx.x;
    if (i >= B_ * NKP) return;
    const int b  = i / NKP;
    const int kk = i - b * NKP;

    float vx, vy, vz;
    if (kpb[kk] != 0) {
        int j0 = kpj[kk * 2 + 0];
        int j1 = kpj[kk * 2 + 1];
        if (j0 < 0 || j0 >= J_) j0 = 0;
        if (j1 < 0 || j1 >= J_) j1 = 0;
        const float* p0 = out + OFF_J + ((size_t)b * J_ + j0) * 3;
        const float* p1 = out + OFF_J + ((size_t)b * J_ + j1) * 3;
        vx = 0.5f * (p0[0] + p1[0]);
        vy = 0.5f * (p0[1] + p1[1]);
        vz = 0.5f * (p0[2] + p1[2]);
    } else {
        vx = vy = vz = 0.0f;
        #pragma unroll
        for (int q = 0; q < 4; ++q) {
            int vid = kpv[kk * 4 + q];
            if (vid < 0 || vid >= VN_) vid = 0;
            const float* p = out + ((size_t)b * VN_ + vid) * 3;
            vx += p[0]; vy += p[1]; vz += p[2];
        }
        vx *= 0.25f; vy *= 0.25f; vz *= 0.25f;
    }
    float* o = out + OFF_K + ((size_t)b * NKP + kk) * 3;
    o[0] = vx; o[1] = vy; o[2] = vz;
}

// ---------------------------------------------------------------------------
extern "C" void kernel_launch(void* const* d_in, const int* in_sizes, int n_in,
                              void* d_out, int out_size, void* d_ws, size_t ws_size,
                              hipStream_t stream) {
    const float* rotvec  = (const float*)d_in[0];
    const float* ptrans  = (const float*)d_in[1];
    const float* vt      = (const float*)d_in[2];
    const float* w       = (const float*)d_in[3];
    const float* tpose   = (const float*)d_in[4];
    const void*  parents = (const void*)d_in[5];
    const int*   kpv     = (const int*)d_in[6];
    const int*   kpj     = (const int*)d_in[7];
    const int*   kpb     = (const int*)d_in[8];

    float* out = (float*)d_out;
    float* Aw  = (float*)d_ws;   // needs B*J*12 floats = 1.72 MB

    chain_kernel<<<B_, 64, 0, stream>>>(rotvec, ptrans, tpose, parents, Aw, out + OFF_J);

    dim3 grid2((VN_ + 255) / 256, B_ / NB);
    lbs_kernel<<<grid2, 256, 0, stream>>>(vt, w, Aw, out);

    kp_kernel<<<(B_ * NKP + 255) / 256, 256, 0, stream>>>(kpv, kpj, kpb, out);
}

// Round 3
// 105.555 us; speedup vs baseline: 2.5187x; 2.5187x over previous
//
#include <hip/hip_runtime.h>

#define B_   256
#define J_   140
#define VN_  14000
#define NKP  22
#define KP   160        // K padded to multiple of 32
#define MP   4096       // M = B*16
#define BN   128        // N-tile (vertices per block)
#define LDP  168        // LDS row stride in bf16 elems (168*2=336B = 21*16, pad kills conflicts)

#define OFF_J (B_ * VN_ * 3)
#define OFF_K (OFF_J + B_ * J_ * 3)

typedef __attribute__((ext_vector_type(8))) __bf16 bf16x8;
typedef __attribute__((ext_vector_type(4))) float  f32x4;

// ---------------------------------------------------------------------------
// Kernel 1: kinematic chain. One wave per batch. Emits A in bf16 GEMM layout:
// Abf[(b*16+comp)*KP + j], comp 12..15 and j>=140 zero-padded. Also J_final.
// ---------------------------------------------------------------------------
__global__ __launch_bounds__(64) void chain_kernel(
    const float* __restrict__ rotvec,
    const float* __restrict__ ptrans,
    const float* __restrict__ tpose,
    const void*  __restrict__ parents_raw,
    __bf16* __restrict__ Abf,          // ws: (MP, KP) bf16
    float*  __restrict__ Jout)         // out+OFF_J
{
    __shared__ float sS[J_][12];
    __shared__ float sG[J_][12];
    __shared__ float sA[J_][12];
    __shared__ int   sPar[J_];
    __shared__ int   sLev[J_];
    __shared__ int   sMax;

    const int b = blockIdx.x;
    const int t = threadIdx.x;

    const int* p32 = (const int*)parents_raw;
    bool is64 = true;
    for (int k = 0; k < J_ / 2; ++k)
        if (p32[2 * k + 1] != 0) { is64 = false; break; }

    for (int j = t; j < J_; j += 64) {
        int p = is64 ? p32[2 * j] : p32[j];
        if (j == 0 || p < 0 || p >= j) p = 0;
        sPar[j] = p;

        const size_t base = ((size_t)b * J_ + j) * 3;
        const float rx = rotvec[base + 0], ry = rotvec[base + 1], rz = rotvec[base + 2];
        const float th  = sqrtf(rx * rx + ry * ry + rz * rz) + 1e-8f;
        const float inv = 1.0f / th;
        const float ux = rx * inv, uy = ry * inv, uz = rz * inv;
        const float c = cosf(th), s = sinf(th);
        const float omc = 1.0f - c;

        sS[j][0]  = c + omc * ux * ux;
        sS[j][1]  = omc * ux * uy - s * uz;
        sS[j][2]  = omc * ux * uz + s * uy;
        sS[j][4]  = omc * uy * ux + s * uz;
        sS[j][5]  = c + omc * uy * uy;
        sS[j][6]  = omc * uy * uz - s * ux;
        sS[j][8]  = omc * uz * ux - s * uy;
        sS[j][9]  = omc * uz * uy + s * ux;
        sS[j][10] = c + omc * uz * uz;
        sS[j][3]  = ptrans[base + 0];
        sS[j][7]  = ptrans[base + 1];
        sS[j][11] = ptrans[base + 2];
    }
    __syncthreads();

    int lmax = 0;
    for (int j = t; j < J_; j += 64) {
        int d = 0, k = j;
        for (int it = 0; it < J_ && k != 0; ++it) { k = sPar[k]; ++d; }
        sLev[j] = d;
        lmax = max(lmax, d);
        if (d == 0) {
            #pragma unroll
            for (int q = 0; q < 12; ++q) sG[j][q] = sS[j][q];
        }
    }
    #pragma unroll
    for (int off = 32; off > 0; off >>= 1)
        lmax = max(lmax, __shfl_xor(lmax, off));
    if (t == 0) sMax = lmax;
    __syncthreads();

    const int maxd = sMax;
    for (int L = 1; L <= maxd; ++L) {
        for (int j = t; j < J_; j += 64) {
            if (sLev[j] == L) {
                const int p = sPar[j];
                float g[12];
                #pragma unroll
                for (int m = 0; m < 3; ++m) {
                    const float a0 = sG[p][m*4+0], a1 = sG[p][m*4+1];
                    const float a2 = sG[p][m*4+2], a3 = sG[p][m*4+3];
                    g[m*4+0] = a0 * sS[j][0] + a1 * sS[j][4] + a2 * sS[j][8];
                    g[m*4+1] = a0 * sS[j][1] + a1 * sS[j][5] + a2 * sS[j][9];
                    g[m*4+2] = a0 * sS[j][2] + a1 * sS[j][6] + a2 * sS[j][10];
                    g[m*4+3] = a0 * sS[j][3] + a1 * sS[j][7] + a2 * sS[j][11] + a3;
                }
                #pragma unroll
                for (int q = 0; q < 12; ++q) sG[j][q] = g[q];
            }
        }
        __syncthreads();
    }

    for (int j = t; j < J_; j += 64) {
        const float tx = tpose[j*3+0], ty = tpose[j*3+1], tz = tpose[j*3+2];
        #pragma unroll
        for (int m = 0; m < 3; ++m) {
            const float r0 = sG[j][m*4+0], r1 = sG[j][m*4+1], r2 = sG[j][m*4+2];
            const float gt = sG[j][m*4+3];
            sA[j][m*4+0] = r0;
            sA[j][m*4+1] = r1;
            sA[j][m*4+2] = r2;
            sA[j][m*4+3] = gt - (r0 * tx + r1 * ty + r2 * tz);
            Jout[((size_t)b * J_ + j) * 3 + m] = gt;
        }
    }
    __syncthreads();

    // write bf16 A rows: comp-major [16][KP]
    for (int idx = t; idx < 16 * KP; idx += 64) {
        const int comp = idx / KP, j = idx % KP;
        const float val = (comp < 12 && j < J_) ? sA[j][comp] : 0.0f;
        Abf[((size_t)b * 16 + comp) * KP + j] = (__bf16)val;
    }
}

// ---------------------------------------------------------------------------
// Kernel 2: weights fp32 (VN,J) -> bf16 (VN,KP) with K zero-pad.
// ---------------------------------------------------------------------------
__global__ __launch_bounds__(256) void prep_w(
    const float* __restrict__ w, __bf16* __restrict__ wbf)
{
    const int id = blockIdx.x * 256 + threadIdx.x;
    if (id >= VN_ * (KP / 8)) return;
    const int v  = id / (KP / 8);
    const int jc = (id % (KP / 8)) * 8;
    __bf16 tmp[8];
    #pragma unroll
    for (int e = 0; e < 8; ++e) {
        const int j = jc + e;
        tmp[e] = (__bf16)((j < J_) ? w[(size_t)v * J_ + j] : 0.0f);
    }
    *reinterpret_cast<int4*>(wbf + (size_t)v * KP + jc) = *reinterpret_cast<int4*>(tmp);
}

// ---------------------------------------------------------------------------
// Kernel 3: GEMM C[4096][14000] = Abf(M,K) * Wbf^T(K,N) with fused LBS epilogue.
// Block: 256 thr (4 waves), tile M=64 (4 batches, one per wave) x N=128.
// Full K (160) staged in LDS, 5 MFMA k-steps of 16x16x32 bf16.
// Lane holds C col = vertex (lane&15), rows = comps (lane>>4)*4+reg ->
// quad q<3 computes output component q directly: acc . (x,y,z,1).
// ---------------------------------------------------------------------------
__global__ __launch_bounds__(256) void gemm_kernel(
    const __bf16* __restrict__ Abf,   // (MP, KP)
    const __bf16* __restrict__ Wbf,   // (VN, KP)  == B^T
    const float*  __restrict__ vt,    // (VN, 3)
    float* __restrict__ out)          // (B, VN, 3)
{
    __shared__ __bf16 sA[64][LDP];
    __shared__ __bf16 sB[BN][LDP];

    const int t  = threadIdx.x;
    const int n0 = blockIdx.x * BN;
    const int m0 = blockIdx.y * 64;

    // stage A-tile: 64 rows x 20 chunks of 8 bf16
    #pragma unroll
    for (int i = 0; i < 5; ++i) {
        const int c = t + i * 256;
        const int row = c / 20, kc = (c % 20) * 8;
        const int4 val = *reinterpret_cast<const int4*>(Abf + (size_t)(m0 + row) * KP + kc);
        *reinterpret_cast<int4*>(&sA[row][kc]) = val;
    }
    // stage B-tile: 128 vertex rows x 20 chunks
    #pragma unroll
    for (int i = 0; i < 10; ++i) {
        const int c = t + i * 256;
        const int row = c / 20, kc = (c % 20) * 8;
        const int v = n0 + row;
        int4 val = {0, 0, 0, 0};
        if (v < VN_)
            val = *reinterpret_cast<const int4*>(Wbf + (size_t)v * KP + kc);
        *reinterpret_cast<int4*>(&sB[row][kc]) = val;
    }
    __syncthreads();

    const int wid   = t >> 6;      // wave id 0..3 -> batch m-row block
    const int lane  = t & 63;
    const int lrow  = lane & 15;   // A row / B col / C col
    const int lquad = lane >> 4;   // k-group; C row group

    // hoist 5 A-fragments (this wave's 16 rows, full K)
    bf16x8 afrag[5];
    #pragma unroll
    for (int s = 0; s < 5; ++s)
        afrag[s] = *reinterpret_cast<const bf16x8*>(&sA[wid * 16 + lrow][s * 32 + lquad * 8]);

    f32x4 acc[8];
    #pragma unroll
    for (int f = 0; f < 8; ++f) {
        f32x4 c = {0.f, 0.f, 0.f, 0.f};
        #pragma unroll
        for (int s = 0; s < 5; ++s) {
            const bf16x8 bfrag = *reinterpret_cast<const bf16x8*>(&sB[f * 16 + lrow][s * 32 + lquad * 8]);
            c = __builtin_amdgcn_mfma_f32_16x16x32_bf16(afrag[s], bfrag, c, 0, 0, 0);
        }
        acc[f] = c;
    }

    // epilogue: batch = m0/16 + wid; component = lquad (<3); vertex = n0+f*16+lrow
    const int batch = (m0 >> 4) + wid;
    if (lquad < 3) {
        #pragma unroll
        for (int f = 0; f < 8; ++f) {
            const int v = n0 + f * 16 + lrow;
            if (v < VN_) {
                const float vx = vt[v * 3 + 0];
                const float vy = vt[v * 3 + 1];
                const float vz = vt[v * 3 + 2];
                const f32x4 c = acc[f];
                out[((size_t)batch * VN_ + v) * 3 + lquad] =
                    c[0] * vx + c[1] * vy + c[2] * vz + c[3];
            }
        }
    }
}

// ---------------------------------------------------------------------------
// Kernel 4: keypoints.
// ---------------------------------------------------------------------------
__global__ __launch_bounds__(256) void kp_kernel(
    const int* __restrict__ kpv, const int* __restrict__ kpj,
    const int* __restrict__ kpb, float* __restrict__ out)
{
    const int i = blockIdx.x * 256 + threadIdx.x;
    if (i >= B_ * NKP) return;
    const int b  = i / NKP;
    const int kk = i - b * NKP;

    float vx, vy, vz;
    if (kpb[kk] != 0) {
        int j0 = kpj[kk * 2 + 0], j1 = kpj[kk * 2 + 1];
        if (j0 < 0 || j0 >= J_) j0 = 0;
        if (j1 < 0 || j1 >= J_) j1 = 0;
        const float* p0 = out + OFF_J + ((size_t)b * J_ + j0) * 3;
        const float* p1 = out + OFF_J + ((size_t)b * J_ + j1) * 3;
        vx = 0.5f * (p0[0] + p1[0]);
        vy = 0.5f * (p0[1] + p1[1]);
        vz = 0.5f * (p0[2] + p1[2]);
    } else {
        vx = vy = vz = 0.0f;
        #pragma unroll
        for (int q = 0; q < 4; ++q) {
            int vid = kpv[kk * 4 + q];
            if (vid < 0 || vid >= VN_) vid = 0;
            const float* p = out + ((size_t)b * VN_ + vid) * 3;
            vx += p[0]; vy += p[1]; vz += p[2];
        }
        vx *= 0.25f; vy *= 0.25f; vz *= 0.25f;
    }
    float* o = out + OFF_K + ((size_t)b * NKP + kk) * 3;
    o[0] = vx; o[1] = vy; o[2] = vz;
}

// ---------------------------------------------------------------------------
extern "C" void kernel_launch(void* const* d_in, const int* in_sizes, int n_in,
                              void* d_out, int out_size, void* d_ws, size_t ws_size,
                              hipStream_t stream) {
    const float* rotvec  = (const float*)d_in[0];
    const float* ptrans  = (const float*)d_in[1];
    const float* vt      = (const float*)d_in[2];
    const float* w       = (const float*)d_in[3];
    const float* tpose   = (const float*)d_in[4];
    const void*  parents = (const void*)d_in[5];
    const int*   kpv     = (const int*)d_in[6];
    const int*   kpj     = (const int*)d_in[7];
    const int*   kpb     = (const int*)d_in[8];

    float*  out = (float*)d_out;
    __bf16* Abf = (__bf16*)d_ws;                         // MP*KP*2 = 1.31 MB
    __bf16* Wbf = (__bf16*)((char*)d_ws + (size_t)MP * KP * 2); // VN*KP*2 = 4.48 MB

    chain_kernel<<<B_, 64, 0, stream>>>(rotvec, ptrans, tpose, parents, Abf, out + OFF_J);

    prep_w<<<(VN_ * (KP / 8) + 255) / 256, 256, 0, stream>>>(w, Wbf);

    dim3 grid((VN_ + BN - 1) / BN, MP / 64);
    gemm_kernel<<<grid, 256, 0, stream>>>(Abf, Wbf, vt, out);

    kp_kernel<<<(B_ * NKP + 255) / 256, 256, 0, stream>>>(kpv, kpj, kpb, out);
}

// Round 4
// 104.658 us; speedup vs baseline: 2.5403x; 1.0086x over previous
//
#include <hip/hip_runtime.h>

#define B_   256
#define J_   140
#define VN_  14000
#define NKP  22
#define KP   160        // K padded to multiple of 32
#define MP   4096       // M = B*16
#define NB_T 64         // N per block (4 frags of 16)

#define OFF_J (B_ * VN_ * 3)
#define OFF_K (OFF_J + B_ * J_ * 3)

typedef __attribute__((ext_vector_type(8))) __bf16 bf16x8;
typedef __attribute__((ext_vector_type(4))) float  f32x4;

// ---------------------------------------------------------------------------
// Kernel 1: kinematic chain. One wave per batch. Emits A in bf16 GEMM layout:
// Abf[(b*16+comp)*KP + j], comp 12..15 and j>=140 zero-padded. Also J_final.
// ---------------------------------------------------------------------------
__global__ __launch_bounds__(64) void chain_kernel(
    const float* __restrict__ rotvec,
    const float* __restrict__ ptrans,
    const float* __restrict__ tpose,
    const void*  __restrict__ parents_raw,
    __bf16* __restrict__ Abf,          // ws: (MP, KP) bf16
    float*  __restrict__ Jout)         // out+OFF_J
{
    __shared__ float sS[J_][12];
    __shared__ float sG[J_][12];
    __shared__ float sA[J_][12];
    __shared__ int   sPar[J_];
    __shared__ int   sLev[J_];
    __shared__ int   sMax;

    const int b = blockIdx.x;
    const int t = threadIdx.x;

    const int* p32 = (const int*)parents_raw;
    bool is64 = true;
    for (int k = 0; k < J_ / 2; ++k)
        if (p32[2 * k + 1] != 0) { is64 = false; break; }

    for (int j = t; j < J_; j += 64) {
        int p = is64 ? p32[2 * j] : p32[j];
        if (j == 0 || p < 0 || p >= j) p = 0;
        sPar[j] = p;

        const size_t base = ((size_t)b * J_ + j) * 3;
        const float rx = rotvec[base + 0], ry = rotvec[base + 1], rz = rotvec[base + 2];
        const float th  = sqrtf(rx * rx + ry * ry + rz * rz) + 1e-8f;
        const float inv = 1.0f / th;
        const float ux = rx * inv, uy = ry * inv, uz = rz * inv;
        const float c = cosf(th), s = sinf(th);
        const float omc = 1.0f - c;

        sS[j][0]  = c + omc * ux * ux;
        sS[j][1]  = omc * ux * uy - s * uz;
        sS[j][2]  = omc * ux * uz + s * uy;
        sS[j][4]  = omc * uy * ux + s * uz;
        sS[j][5]  = c + omc * uy * uy;
        sS[j][6]  = omc * uy * uz - s * ux;
        sS[j][8]  = omc * uz * ux - s * uy;
        sS[j][9]  = omc * uz * uy + s * ux;
        sS[j][10] = c + omc * uz * uz;
        sS[j][3]  = ptrans[base + 0];
        sS[j][7]  = ptrans[base + 1];
        sS[j][11] = ptrans[base + 2];
    }
    __syncthreads();

    int lmax = 0;
    for (int j = t; j < J_; j += 64) {
        int d = 0, k = j;
        for (int it = 0; it < J_ && k != 0; ++it) { k = sPar[k]; ++d; }
        sLev[j] = d;
        lmax = max(lmax, d);
        if (d == 0) {
            #pragma unroll
            for (int q = 0; q < 12; ++q) sG[j][q] = sS[j][q];
        }
    }
    #pragma unroll
    for (int off = 32; off > 0; off >>= 1)
        lmax = max(lmax, __shfl_xor(lmax, off));
    if (t == 0) sMax = lmax;
    __syncthreads();

    const int maxd = sMax;
    for (int L = 1; L <= maxd; ++L) {
        for (int j = t; j < J_; j += 64) {
            if (sLev[j] == L) {
                const int p = sPar[j];
                float g[12];
                #pragma unroll
                for (int m = 0; m < 3; ++m) {
                    const float a0 = sG[p][m*4+0], a1 = sG[p][m*4+1];
                    const float a2 = sG[p][m*4+2], a3 = sG[p][m*4+3];
                    g[m*4+0] = a0 * sS[j][0] + a1 * sS[j][4] + a2 * sS[j][8];
                    g[m*4+1] = a0 * sS[j][1] + a1 * sS[j][5] + a2 * sS[j][9];
                    g[m*4+2] = a0 * sS[j][2] + a1 * sS[j][6] + a2 * sS[j][10];
                    g[m*4+3] = a0 * sS[j][3] + a1 * sS[j][7] + a2 * sS[j][11] + a3;
                }
                #pragma unroll
                for (int q = 0; q < 12; ++q) sG[j][q] = g[q];
            }
        }
        __syncthreads();
    }

    for (int j = t; j < J_; j += 64) {
        const float tx = tpose[j*3+0], ty = tpose[j*3+1], tz = tpose[j*3+2];
        #pragma unroll
        for (int m = 0; m < 3; ++m) {
            const float r0 = sG[j][m*4+0], r1 = sG[j][m*4+1], r2 = sG[j][m*4+2];
            const float gt = sG[j][m*4+3];
            sA[j][m*4+0] = r0;
            sA[j][m*4+1] = r1;
            sA[j][m*4+2] = r2;
            sA[j][m*4+3] = gt - (r0 * tx + r1 * ty + r2 * tz);
            Jout[((size_t)b * J_ + j) * 3 + m] = gt;
        }
    }
    __syncthreads();

    for (int idx = t; idx < 16 * KP; idx += 64) {
        const int comp = idx / KP, j = idx % KP;
        const float val = (comp < 12 && j < J_) ? sA[j][comp] : 0.0f;
        Abf[((size_t)b * 16 + comp) * KP + j] = (__bf16)val;
    }
}

// ---------------------------------------------------------------------------
// Kernel 2: weights fp32 (VN,J) -> bf16 (VN,KP) with K zero-pad.
// ---------------------------------------------------------------------------
__global__ __launch_bounds__(256) void prep_w(
    const float* __restrict__ w, __bf16* __restrict__ wbf)
{
    const int id = blockIdx.x * 256 + threadIdx.x;
    if (id >= VN_ * (KP / 8)) return;
    const int v  = id / (KP / 8);
    const int jc = (id % (KP / 8)) * 8;
    __bf16 tmp[8];
    #pragma unroll
    for (int e = 0; e < 8; ++e) {
        const int j = jc + e;
        tmp[e] = (__bf16)((j < J_) ? w[(size_t)v * J_ + j] : 0.0f);
    }
    *reinterpret_cast<int4*>(wbf + (size_t)v * KP + jc) = *reinterpret_cast<int4*>(tmp);
}

// ---------------------------------------------------------------------------
// Kernel 3: register-direct GEMM + fused LBS epilogue. NO LDS, no barriers.
// Block = 4 waves, all on the same N-range (L1 shares B-frags); wave `wid`
// owns 4 batches (M=64). Per wave: M=64 x N=64 x K=160 -> 80 MFMA.
// Fragments load straight from global (L2-resident; 16x64B lines per instr).
// C-layout: col = vertex (lane&15), row = comp ((lane>>4)*4+reg).
// ---------------------------------------------------------------------------
__global__ __launch_bounds__(256, 4) void gemm_kernel(
    const __bf16* __restrict__ Abf,   // (MP, KP)
    const __bf16* __restrict__ Wbf,   // (VN, KP)  == B^T
    const float*  __restrict__ vt,    // (VN, 3)
    float* __restrict__ out)          // (B, VN, 3)
{
    const int t     = threadIdx.x;
    const int wid   = t >> 6;
    const int lane  = t & 63;
    const int lrow  = lane & 15;
    const int lquad = lane >> 4;

    const int n0 = blockIdx.x * NB_T;             // vertex base of block
    const int b0 = blockIdx.y * 16 + wid * 4;     // batch base of wave

    f32x4 acc[4][4];
    #pragma unroll
    for (int mb = 0; mb < 4; ++mb)
        #pragma unroll
        for (int f = 0; f < 4; ++f)
            acc[mb][f] = (f32x4){0.f, 0.f, 0.f, 0.f};

    const int kofs = lquad * 8;                   // k offset within 32-chunk

    #pragma unroll
    for (int s = 0; s < 5; ++s) {
        bf16x8 afrag[4];
        #pragma unroll
        for (int mb = 0; mb < 4; ++mb)
            afrag[mb] = *reinterpret_cast<const bf16x8*>(
                Abf + ((size_t)(b0 + mb) * 16 + lrow) * KP + s * 32 + kofs);

        #pragma unroll
        for (int f = 0; f < 4; ++f) {
            int v = n0 + f * 16 + lrow;
            if (v >= VN_) v = VN_ - 1;            // clamp (masked at store)
            const bf16x8 bfrag = *reinterpret_cast<const bf16x8*>(
                Wbf + (size_t)v * KP + s * 32 + kofs);
            #pragma unroll
            for (int mb = 0; mb < 4; ++mb)
                acc[mb][f] = __builtin_amdgcn_mfma_f32_16x16x32_bf16(
                    afrag[mb], bfrag, acc[mb][f], 0, 0, 0);
        }
    }

    // epilogue: comp = lquad (<3); vertex = n0 + f*16 + lrow
    if (lquad < 3) {
        #pragma unroll
        for (int f = 0; f < 4; ++f) {
            const int v = n0 + f * 16 + lrow;
            if (v < VN_) {
                const float vx = vt[v * 3 + 0];
                const float vy = vt[v * 3 + 1];
                const float vz = vt[v * 3 + 2];
                #pragma unroll
                for (int mb = 0; mb < 4; ++mb) {
                    const f32x4 c = acc[mb][f];
                    out[((size_t)(b0 + mb) * VN_ + v) * 3 + lquad] =
                        c[0] * vx + c[1] * vy + c[2] * vz + c[3];
                }
            }
        }
    }
}

// ---------------------------------------------------------------------------
// Kernel 4: keypoints.
// ---------------------------------------------------------------------------
__global__ __launch_bounds__(256) void kp_kernel(
    const int* __restrict__ kpv, const int* __restrict__ kpj,
    const int* __restrict__ kpb, float* __restrict__ out)
{
    const int i = blockIdx.x * 256 + threadIdx.x;
    if (i >= B_ * NKP) return;
    const int b  = i / NKP;
    const int kk = i - b * NKP;

    float vx, vy, vz;
    if (kpb[kk] != 0) {
        int j0 = kpj[kk * 2 + 0], j1 = kpj[kk * 2 + 1];
        if (j0 < 0 || j0 >= J_) j0 = 0;
        if (j1 < 0 || j1 >= J_) j1 = 0;
        const float* p0 = out + OFF_J + ((size_t)b * J_ + j0) * 3;
        const float* p1 = out + OFF_J + ((size_t)b * J_ + j1) * 3;
        vx = 0.5f * (p0[0] + p1[0]);
        vy = 0.5f * (p0[1] + p1[1]);
        vz = 0.5f * (p0[2] + p1[2]);
    } else {
        vx = vy = vz = 0.0f;
        #pragma unroll
        for (int q = 0; q < 4; ++q) {
            int vid = kpv[kk * 4 + q];
            if (vid < 0 || vid >= VN_) vid = 0;
            const float* p = out + ((size_t)b * VN_ + vid) * 3;
            vx += p[0]; vy += p[1]; vz += p[2];
        }
        vx *= 0.25f; vy *= 0.25f; vz *= 0.25f;
    }
    float* o = out + OFF_K + ((size_t)b * NKP + kk) * 3;
    o[0] = vx; o[1] = vy; o[2] = vz;
}

// ---------------------------------------------------------------------------
extern "C" void kernel_launch(void* const* d_in, const int* in_sizes, int n_in,
                              void* d_out, int out_size, void* d_ws, size_t ws_size,
                              hipStream_t stream) {
    const float* rotvec  = (const float*)d_in[0];
    const float* ptrans  = (const float*)d_in[1];
    const float* vt      = (const float*)d_in[2];
    const float* w       = (const float*)d_in[3];
    const float* tpose   = (const float*)d_in[4];
    const void*  parents = (const void*)d_in[5];
    const int*   kpv     = (const int*)d_in[6];
    const int*   kpj     = (const int*)d_in[7];
    const int*   kpb     = (const int*)d_in[8];

    float*  out = (float*)d_out;
    __bf16* Abf = (__bf16*)d_ws;                              // MP*KP*2 = 1.31 MB
    __bf16* Wbf = (__bf16*)((char*)d_ws + (size_t)MP * KP * 2); // VN*KP*2 = 4.48 MB

    chain_kernel<<<B_, 64, 0, stream>>>(rotvec, ptrans, tpose, parents, Abf, out + OFF_J);

    prep_w<<<(VN_ * (KP / 8) + 255) / 256, 256, 0, stream>>>(w, Wbf);

    dim3 grid((VN_ + NB_T - 1) / NB_T, MP / (16 * 16));   // (219, 16)
    gemm_kernel<<<grid, 256, 0, stream>>>(Abf, Wbf, vt, out);

    kp_kernel<<<(B_ * NKP + 255) / 256, 256, 0, stream>>>(kpv, kpj, kpb, out);
}

// Round 5
// 70.916 us; speedup vs baseline: 3.7490x; 1.4758x over previous
//
#include <hip/hip_runtime.h>

#define B_   256
#define J_   140
#define VN_  14000
#define NKP  22
#define KP   160        // K padded to multiple of 32
#define MP   4096       // M = B*16
#define NSPLIT 16
#define NT   219        // ceil(VN/64) N-tiles of 64 vertices

#define OFF_J (B_ * VN_ * 3)
#define OFF_K (OFF_J + B_ * J_ * 3)

typedef __attribute__((ext_vector_type(8))) __bf16 bf16x8;
typedef __attribute__((ext_vector_type(4))) float  f32x4;
typedef unsigned int u32;

__device__ __forceinline__ void gload_lds16(const void* g, void* l) {
    __builtin_amdgcn_global_load_lds(
        (const __attribute__((address_space(1))) u32*)g,
        (__attribute__((address_space(3))) u32*)l, 16, 0, 0);
}

// ---------------------------------------------------------------------------
// Kernel 1: kinematic chain. One wave per batch. Emits A in bf16 GEMM layout:
// Abf[(b*16+comp)*KP + j], comp 12..15 and j>=140 zero. Also J_final.
// ---------------------------------------------------------------------------
__global__ __launch_bounds__(64) void chain_kernel(
    const float* __restrict__ rotvec,
    const float* __restrict__ ptrans,
    const float* __restrict__ tpose,
    const void*  __restrict__ parents_raw,
    __bf16* __restrict__ Abf,
    float*  __restrict__ Jout)
{
    __shared__ float sS[J_][12];
    __shared__ float sG[J_][12];
    __shared__ float sA[J_][12];
    __shared__ int   sPar[J_];
    __shared__ int   sLev[J_];
    __shared__ int   sMax;

    const int b = blockIdx.x;
    const int t = threadIdx.x;

    const int* p32 = (const int*)parents_raw;
    bool is64 = true;
    for (int k = 0; k < J_ / 2; ++k)
        if (p32[2 * k + 1] != 0) { is64 = false; break; }

    for (int j = t; j < J_; j += 64) {
        int p = is64 ? p32[2 * j] : p32[j];
        if (j == 0 || p < 0 || p >= j) p = 0;
        sPar[j] = p;

        const size_t base = ((size_t)b * J_ + j) * 3;
        const float rx = rotvec[base + 0], ry = rotvec[base + 1], rz = rotvec[base + 2];
        const float th  = sqrtf(rx * rx + ry * ry + rz * rz) + 1e-8f;
        const float inv = 1.0f / th;
        const float ux = rx * inv, uy = ry * inv, uz = rz * inv;
        const float c = cosf(th), s = sinf(th);
        const float omc = 1.0f - c;

        sS[j][0]  = c + omc * ux * ux;
        sS[j][1]  = omc * ux * uy - s * uz;
        sS[j][2]  = omc * ux * uz + s * uy;
        sS[j][4]  = omc * uy * ux + s * uz;
        sS[j][5]  = c + omc * uy * uy;
        sS[j][6]  = omc * uy * uz - s * ux;
        sS[j][8]  = omc * uz * ux - s * uy;
        sS[j][9]  = omc * uz * uy + s * ux;
        sS[j][10] = c + omc * uz * uz;
        sS[j][3]  = ptrans[base + 0];
        sS[j][7]  = ptrans[base + 1];
        sS[j][11] = ptrans[base + 2];
    }
    __syncthreads();

    int lmax = 0;
    for (int j = t; j < J_; j += 64) {
        int d = 0, k = j;
        for (int it = 0; it < J_ && k != 0; ++it) { k = sPar[k]; ++d; }
        sLev[j] = d;
        lmax = max(lmax, d);
        if (d == 0) {
            #pragma unroll
            for (int q = 0; q < 12; ++q) sG[j][q] = sS[j][q];
        }
    }
    #pragma unroll
    for (int off = 32; off > 0; off >>= 1)
        lmax = max(lmax, __shfl_xor(lmax, off));
    if (t == 0) sMax = lmax;
    __syncthreads();

    const int maxd = sMax;
    for (int L = 1; L <= maxd; ++L) {
        for (int j = t; j < J_; j += 64) {
            if (sLev[j] == L) {
                const int p = sPar[j];
                float g[12];
                #pragma unroll
                for (int m = 0; m < 3; ++m) {
                    const float a0 = sG[p][m*4+0], a1 = sG[p][m*4+1];
                    const float a2 = sG[p][m*4+2], a3 = sG[p][m*4+3];
                    g[m*4+0] = a0 * sS[j][0] + a1 * sS[j][4] + a2 * sS[j][8];
                    g[m*4+1] = a0 * sS[j][1] + a1 * sS[j][5] + a2 * sS[j][9];
                    g[m*4+2] = a0 * sS[j][2] + a1 * sS[j][6] + a2 * sS[j][10];
                    g[m*4+3] = a0 * sS[j][3] + a1 * sS[j][7] + a2 * sS[j][11] + a3;
                }
                #pragma unroll
                for (int q = 0; q < 12; ++q) sG[j][q] = g[q];
            }
        }
        __syncthreads();
    }

    for (int j = t; j < J_; j += 64) {
        const float tx = tpose[j*3+0], ty = tpose[j*3+1], tz = tpose[j*3+2];
        #pragma unroll
        for (int m = 0; m < 3; ++m) {
            const float r0 = sG[j][m*4+0], r1 = sG[j][m*4+1], r2 = sG[j][m*4+2];
            const float gt = sG[j][m*4+3];
            sA[j][m*4+0] = r0;
            sA[j][m*4+1] = r1;
            sA[j][m*4+2] = r2;
            sA[j][m*4+3] = gt - (r0 * tx + r1 * ty + r2 * tz);
            Jout[((size_t)b * J_ + j) * 3 + m] = gt;
        }
    }
    __syncthreads();

    for (int idx = t; idx < 16 * KP; idx += 64) {
        const int comp = idx / KP, j = idx % KP;
        const float val = (comp < 12 && j < J_) ? sA[j][comp] : 0.0f;
        Abf[((size_t)b * 16 + comp) * KP + j] = (__bf16)val;
    }
}

// ---------------------------------------------------------------------------
// Kernel 2: weights fp32 (VN,J) -> bf16 (VN,KP), K zero-padded.
// ---------------------------------------------------------------------------
__global__ __launch_bounds__(256) void prep_w(
    const float* __restrict__ w, __bf16* __restrict__ wbf)
{
    const int id = blockIdx.x * 256 + threadIdx.x;
    if (id >= VN_ * (KP / 8)) return;
    const int v  = id / (KP / 8);
    const int jc = (id % (KP / 8)) * 8;
    __bf16 tmp[8];
    #pragma unroll
    for (int e = 0; e < 8; ++e) {
        const int j = jc + e;
        tmp[e] = (__bf16)((j < J_) ? w[(size_t)v * J_ + j] : 0.0f);
    }
    *reinterpret_cast<int4*>(wbf + (size_t)v * KP + jc) = *reinterpret_cast<int4*>(tmp);
}

// ---------------------------------------------------------------------------
// Kernel 3: persistent-A, streamed-B GEMM + fused LBS epilogue.
// Block = 256 thr (4 waves), M=128 rows (8 batches) resident in LDS,
// N-loop over 64-vertex tiles (stride NSPLIT), B double-buffered via
// global_load_lds into fragment-order LDS (zero bank conflicts, linear dest).
// Wave w: batches {2w, 2w+1}; afrags hoisted to VGPR once.
// Epilogue: shfl-transpose comps to quad0, dense float3 stores.
// ---------------------------------------------------------------------------
__global__ __launch_bounds__(256, 2) void gemm_kernel(
    const __bf16* __restrict__ Abf,   // (MP, KP)
    const __bf16* __restrict__ Wbf,   // (VN, KP)
    const float*  __restrict__ vt,    // (VN, 3)
    float* __restrict__ out)          // (B, VN, 3)
{
    __shared__ __bf16 sA[8 * 5 * 64 * 8];       // 40 KB, [mb][s][lane]x16B
    __shared__ __bf16 sB[2][4 * 5 * 64 * 8];    // 2x20 KB, [f][s][lane]x16B

    const int lane = threadIdx.x & 63;
    const int w    = threadIdx.x >> 6;
    const int r    = lane & 15;
    const int q16  = (lane >> 4) * 16;          // byte offset of k-quad
    const int row0   = blockIdx.y * 128;        // A-row base
    const int batch0 = blockIdx.y * 8;

    // ---- stage A once: wave w stages mb = 2w, 2w+1 (10 x 1KB groups)
    #pragma unroll
    for (int mi = 0; mi < 2; ++mi) {
        const int mb = w * 2 + mi;
        const char* g = (const char*)(Abf + (size_t)(row0 + mb * 16 + r) * KP) + q16;
        char* lb = (char*)sA + mb * 5 * 1024;
        #pragma unroll
        for (int s = 0; s < 5; ++s)
            gload_lds16(g + s * 64, lb + s * 1024);
    }
    // ---- stage B tile 0: wave w stages frag f = w
    {
        int v = blockIdx.x * 64 + w * 16 + r;
        if (v >= VN_) v = VN_ - 1;
        const char* g = (const char*)(Wbf + (size_t)v * KP) + q16;
        char* lb = (char*)&sB[0][0] + w * 5 * 1024;
        #pragma unroll
        for (int s = 0; s < 5; ++s)
            gload_lds16(g + s * 64, lb + s * 1024);
    }
    asm volatile("s_waitcnt vmcnt(0)" ::: "memory");
    __syncthreads();

    // ---- hoist A fragments (whole kernel lifetime): 2x5 bf16x8 = 40 VGPR
    bf16x8 afrag[2][5];
    #pragma unroll
    for (int mi = 0; mi < 2; ++mi)
        #pragma unroll
        for (int s = 0; s < 5; ++s)
            afrag[mi][s] = *reinterpret_cast<const bf16x8*>(
                &sA[(((w * 2 + mi) * 5 + s) * 64 + lane) * 8]);

    int cur = 0;
    for (int t = blockIdx.x; t < NT; t += NSPLIT) {
        // ---- prefetch next B tile into other buffer (async)
        const int tn = t + NSPLIT;
        if (tn < NT) {
            int v = tn * 64 + w * 16 + r;
            if (v >= VN_) v = VN_ - 1;
            const char* g = (const char*)(Wbf + (size_t)v * KP) + q16;
            char* lb = (char*)&sB[cur ^ 1][0] + w * 5 * 1024;
            #pragma unroll
            for (int s = 0; s < 5; ++s)
                gload_lds16(g + s * 64, lb + s * 1024);
        }

        // ---- compute: 40 MFMA per wave from sB[cur]
        f32x4 acc[2][4];
        #pragma unroll
        for (int mi = 0; mi < 2; ++mi)
            #pragma unroll
            for (int f = 0; f < 4; ++f)
                acc[mi][f] = (f32x4){0.f, 0.f, 0.f, 0.f};

        #pragma unroll
        for (int f = 0; f < 4; ++f) {
            #pragma unroll
            for (int s = 0; s < 5; ++s) {
                const bf16x8 bf = *reinterpret_cast<const bf16x8*>(
                    &sB[cur][((f * 5 + s) * 64 + lane) * 8]);
                acc[0][f] = __builtin_amdgcn_mfma_f32_16x16x32_bf16(
                    afrag[0][s], bf, acc[0][f], 0, 0, 0);
                acc[1][f] = __builtin_amdgcn_mfma_f32_16x16x32_bf16(
                    afrag[1][s], bf, acc[1][f], 0, 0, 0);
            }
        }

        // ---- fused epilogue: val = T . (x,y,z,1); comp = quad (0..2)
        const int n0 = t * 64;
        #pragma unroll
        for (int f = 0; f < 4; ++f) {
            const int v  = n0 + f * 16 + r;
            const int vc = (v < VN_) ? v : VN_ - 1;
            const float3 p = *reinterpret_cast<const float3*>(vt + 3 * (size_t)vc);
            #pragma unroll
            for (int mi = 0; mi < 2; ++mi) {
                const f32x4 c = acc[mi][f];
                const float val = c[0] * p.x + c[1] * p.y + c[2] * p.z + c[3];
                const float xx = __shfl(val, r);
                const float yy = __shfl(val, 16 + r);
                const float zz = __shfl(val, 32 + r);
                if (lane < 16 && v < VN_) {
                    float* o = out + ((size_t)(batch0 + w * 2 + mi) * VN_ + v) * 3;
                    *reinterpret_cast<float3*>(o) = make_float3(xx, yy, zz);
                }
            }
        }

        asm volatile("s_waitcnt vmcnt(0)" ::: "memory");
        __syncthreads();
        cur ^= 1;
    }
}

// ---------------------------------------------------------------------------
// Kernel 4: keypoints.
// ---------------------------------------------------------------------------
__global__ __launch_bounds__(256) void kp_kernel(
    const int* __restrict__ kpv, const int* __restrict__ kpj,
    const int* __restrict__ kpb, float* __restrict__ out)
{
    const int i = blockIdx.x * 256 + threadIdx.x;
    if (i >= B_ * NKP) return;
    const int b  = i / NKP;
    const int kk = i - b * NKP;

    float vx, vy, vz;
    if (kpb[kk] != 0) {
        int j0 = kpj[kk * 2 + 0], j1 = kpj[kk * 2 + 1];
        if (j0 < 0 || j0 >= J_) j0 = 0;
        if (j1 < 0 || j1 >= J_) j1 = 0;
        const float* p0 = out + OFF_J + ((size_t)b * J_ + j0) * 3;
        const float* p1 = out + OFF_J + ((size_t)b * J_ + j1) * 3;
        vx = 0.5f * (p0[0] + p1[0]);
        vy = 0.5f * (p0[1] + p1[1]);
        vz = 0.5f * (p0[2] + p1[2]);
    } else {
        vx = vy = vz = 0.0f;
        #pragma unroll
        for (int q = 0; q < 4; ++q) {
            int vid = kpv[kk * 4 + q];
            if (vid < 0 || vid >= VN_) vid = 0;
            const float* p = out + ((size_t)b * VN_ + vid) * 3;
            vx += p[0]; vy += p[1]; vz += p[2];
        }
        vx *= 0.25f; vy *= 0.25f; vz *= 0.25f;
    }
    float* o = out + OFF_K + ((size_t)b * NKP + kk) * 3;
    o[0] = vx; o[1] = vy; o[2] = vz;
}

// ---------------------------------------------------------------------------
extern "C" void kernel_launch(void* const* d_in, const int* in_sizes, int n_in,
                              void* d_out, int out_size, void* d_ws, size_t ws_size,
                              hipStream_t stream) {
    const float* rotvec  = (const float*)d_in[0];
    const float* ptrans  = (const float*)d_in[1];
    const float* vt      = (const float*)d_in[2];
    const float* w       = (const float*)d_in[3];
    const float* tpose   = (const float*)d_in[4];
    const void*  parents = (const void*)d_in[5];
    const int*   kpv     = (const int*)d_in[6];
    const int*   kpj     = (const int*)d_in[7];
    const int*   kpb     = (const int*)d_in[8];

    float*  out = (float*)d_out;
    __bf16* Abf = (__bf16*)d_ws;                               // 1.31 MB
    __bf16* Wbf = (__bf16*)((char*)d_ws + (size_t)MP * KP * 2); // 4.48 MB

    chain_kernel<<<B_, 64, 0, stream>>>(rotvec, ptrans, tpose, parents, Abf, out + OFF_J);

    prep_w<<<(VN_ * (KP / 8) + 255) / 256, 256, 0, stream>>>(w, Wbf);

    dim3 grid(NSPLIT, MP / 128);    // (16, 32) = 512 blocks
    gemm_kernel<<<grid, 256, 0, stream>>>(Abf, Wbf, vt, out);

    kp_kernel<<<(B_ * NKP + 255) / 256, 256, 0, stream>>>(kpv, kpj, kpb, out);
}

// Round 6
// 50.156 us; speedup vs baseline: 5.3007x; 1.4139x over previous
//
#include <hip/hip_runtime.h>

#define B_   256
#define J_   140
#define VN_  14000
#define NKP  22
#define KP   160        // K padded to multiple of 32
#define MP   4096       // M = B*16
#define NSPLIT 32
#define NT   219        // ceil(VN/64) N-tiles of 64 vertices

#define OFF_J (B_ * VN_ * 3)
#define OFF_K (OFF_J + B_ * J_ * 3)

#define PREPW_BLOCKS ((VN_ * (KP / 8) + 255) / 256)

typedef __attribute__((ext_vector_type(8))) __bf16 bf16x8;
typedef __attribute__((ext_vector_type(4))) float  f32x4;
typedef unsigned int u32;

__device__ __forceinline__ void gload_lds16(const void* g, void* l) {
    __builtin_amdgcn_global_load_lds(
        (const __attribute__((address_space(1))) u32*)g,
        (__attribute__((address_space(3))) u32*)l, 16, 0, 0);
}

// ---------------------------------------------------------------------------
// Kernel 1 (fused): blocks [0, B_) run the kinematic chain (one block per
// batch, 256 threads); blocks [B_, B_+PREPW_BLOCKS) convert weights to bf16.
// chain emits Abf[(b*16+comp)*KP + j] (comp 12..15, j>=140 zero) + J_final.
// ---------------------------------------------------------------------------
__global__ __launch_bounds__(256) void prep_kernel(
    const float* __restrict__ rotvec,
    const float* __restrict__ ptrans,
    const float* __restrict__ tpose,
    const void*  __restrict__ parents_raw,
    const float* __restrict__ w,
    __bf16* __restrict__ Abf,
    __bf16* __restrict__ Wbf,
    float*  __restrict__ Jout)
{
    // ---------------- weights cast part ----------------
    if (blockIdx.x >= B_) {
        const int id = (blockIdx.x - B_) * 256 + threadIdx.x;
        if (id < VN_ * (KP / 8)) {
            const int v  = id / (KP / 8);
            const int jc = (id % (KP / 8)) * 8;
            __bf16 tmp[8];
            #pragma unroll
            for (int e = 0; e < 8; ++e) {
                const int j = jc + e;
                tmp[e] = (__bf16)((j < J_) ? w[(size_t)v * J_ + j] : 0.0f);
            }
            *reinterpret_cast<int4*>(Wbf + (size_t)v * KP + jc) =
                *reinterpret_cast<int4*>(tmp);
        }
        return;
    }

    // ---------------- chain part ----------------
    __shared__ float sS[J_][12];
    __shared__ float sG[J_][12];
    __shared__ float sA[J_][12];
    __shared__ int   sPar[J_];
    __shared__ int   sLev[J_];
    __shared__ int   sMax;

    const int b = blockIdx.x;
    const int t = threadIdx.x;
    if (t == 0) sMax = 0;

    const int* p32 = (const int*)parents_raw;
    bool is64 = true;
    for (int k = 0; k < J_ / 2; ++k)
        if (p32[2 * k + 1] != 0) { is64 = false; break; }

    for (int j = t; j < J_; j += 256) {
        int p = is64 ? p32[2 * j] : p32[j];
        if (j == 0 || p < 0 || p >= j) p = 0;
        sPar[j] = p;

        const size_t base = ((size_t)b * J_ + j) * 3;
        const float rx = rotvec[base + 0], ry = rotvec[base + 1], rz = rotvec[base + 2];
        const float th  = sqrtf(rx * rx + ry * ry + rz * rz) + 1e-8f;
        const float inv = 1.0f / th;
        const float ux = rx * inv, uy = ry * inv, uz = rz * inv;
        const float c = cosf(th), s = sinf(th);
        const float omc = 1.0f - c;

        sS[j][0]  = c + omc * ux * ux;
        sS[j][1]  = omc * ux * uy - s * uz;
        sS[j][2]  = omc * ux * uz + s * uy;
        sS[j][4]  = omc * uy * ux + s * uz;
        sS[j][5]  = c + omc * uy * uy;
        sS[j][6]  = omc * uy * uz - s * ux;
        sS[j][8]  = omc * uz * ux - s * uy;
        sS[j][9]  = omc * uz * uy + s * ux;
        sS[j][10] = c + omc * uz * uz;
        sS[j][3]  = ptrans[base + 0];
        sS[j][7]  = ptrans[base + 1];
        sS[j][11] = ptrans[base + 2];
    }
    __syncthreads();

    for (int j = t; j < J_; j += 256) {
        int d = 0, k = j;
        for (int it = 0; it < J_ && k != 0; ++it) { k = sPar[k]; ++d; }
        sLev[j] = d;
        atomicMax(&sMax, d);
        if (d == 0) {
            #pragma unroll
            for (int q = 0; q < 12; ++q) sG[j][q] = sS[j][q];
        }
    }
    __syncthreads();

    const int maxd = sMax;
    for (int L = 1; L <= maxd; ++L) {
        for (int j = t; j < J_; j += 256) {
            if (sLev[j] == L) {
                const int p = sPar[j];
                float g[12];
                #pragma unroll
                for (int m = 0; m < 3; ++m) {
                    const float a0 = sG[p][m*4+0], a1 = sG[p][m*4+1];
                    const float a2 = sG[p][m*4+2], a3 = sG[p][m*4+3];
                    g[m*4+0] = a0 * sS[j][0] + a1 * sS[j][4] + a2 * sS[j][8];
                    g[m*4+1] = a0 * sS[j][1] + a1 * sS[j][5] + a2 * sS[j][9];
                    g[m*4+2] = a0 * sS[j][2] + a1 * sS[j][6] + a2 * sS[j][10];
                    g[m*4+3] = a0 * sS[j][3] + a1 * sS[j][7] + a2 * sS[j][11] + a3;
                }
                #pragma unroll
                for (int q = 0; q < 12; ++q) sG[j][q] = g[q];
            }
        }
        __syncthreads();
    }

    for (int j = t; j < J_; j += 256) {
        const float tx = tpose[j*3+0], ty = tpose[j*3+1], tz = tpose[j*3+2];
        #pragma unroll
        for (int m = 0; m < 3; ++m) {
            const float r0 = sG[j][m*4+0], r1 = sG[j][m*4+1], r2 = sG[j][m*4+2];
            const float gt = sG[j][m*4+3];
            sA[j][m*4+0] = r0;
            sA[j][m*4+1] = r1;
            sA[j][m*4+2] = r2;
            sA[j][m*4+3] = gt - (r0 * tx + r1 * ty + r2 * tz);
            Jout[((size_t)b * J_ + j) * 3 + m] = gt;
        }
    }
    __syncthreads();

    for (int idx = t; idx < 16 * KP; idx += 256) {
        const int comp = idx / KP, j = idx % KP;
        const float val = (comp < 12 && j < J_) ? sA[j][comp] : 0.0f;
        Abf[((size_t)b * 16 + comp) * KP + j] = (__bf16)val;
    }
}

// ---------------------------------------------------------------------------
// Kernel 2: GEMM + fused LBS epilogue.
// Block = 4 waves; wave owns 2 batches (A-frags in 40 VGPR, loaded from L2).
// B double-buffered in LDS (2x20KB -> 4 blocks/CU) via global_load_lds in
// fragment-order (conflict-free). Loop: prefetch-issue -> MFMA -> vmcnt(0)
// -> barrier -> epilogue (shfl-transpose + dense float3 stores, overlapped
// with next iteration's compute).
// ---------------------------------------------------------------------------
__global__ __launch_bounds__(256, 4) void gemm_kernel(
    const __bf16* __restrict__ Abf,   // (MP, KP)
    const __bf16* __restrict__ Wbf,   // (VN, KP)
    const float*  __restrict__ vt,    // (VN, 3)
    float* __restrict__ out)          // (B, VN, 3)
{
    __shared__ __bf16 sB[2][4 * 5 * 64 * 8];    // 2 x 20 KB

    const int lane = threadIdx.x & 63;
    const int w    = threadIdx.x >> 6;
    const int r    = lane & 15;
    const int q16  = (lane >> 4) * 16;          // byte offset of k-quad
    const int batch0 = blockIdx.y * 8;
    const int row0   = blockIdx.y * 128;

    // ---- A fragments straight from global (L2-hot): 2 x 5 x 16B per lane
    bf16x8 afrag[2][5];
    #pragma unroll
    for (int mi = 0; mi < 2; ++mi) {
        const char* g = (const char*)(Abf + (size_t)(row0 + (w * 2 + mi) * 16 + r) * KP) + q16;
        #pragma unroll
        for (int s = 0; s < 5; ++s)
            afrag[mi][s] = *reinterpret_cast<const bf16x8*>(g + s * 64);
    }

    // ---- stage B tile 0: wave w stages frag f = w
    {
        int v = blockIdx.x * 64 + w * 16 + r;
        if (v >= VN_) v = VN_ - 1;
        const char* g = (const char*)(Wbf + (size_t)v * KP) + q16;
        char* lb = (char*)&sB[0][0] + w * 5 * 1024;
        #pragma unroll
        for (int s = 0; s < 5; ++s)
            gload_lds16(g + s * 64, lb + s * 1024);
    }
    asm volatile("s_waitcnt vmcnt(0)" ::: "memory");
    __syncthreads();

    int cur = 0;
    for (int t = blockIdx.x; t < NT; t += NSPLIT) {
        // ---- prefetch next B tile into other buffer (async)
        const int tn = t + NSPLIT;
        if (tn < NT) {
            int v = tn * 64 + w * 16 + r;
            if (v >= VN_) v = VN_ - 1;
            const char* g = (const char*)(Wbf + (size_t)v * KP) + q16;
            char* lb = (char*)&sB[cur ^ 1][0] + w * 5 * 1024;
            #pragma unroll
            for (int s = 0; s < 5; ++s)
                gload_lds16(g + s * 64, lb + s * 1024);
        }

        // ---- compute: 40 MFMA per wave from sB[cur]
        f32x4 acc[2][4];
        #pragma unroll
        for (int mi = 0; mi < 2; ++mi)
            #pragma unroll
            for (int f = 0; f < 4; ++f)
                acc[mi][f] = (f32x4){0.f, 0.f, 0.f, 0.f};

        #pragma unroll
        for (int f = 0; f < 4; ++f) {
            #pragma unroll
            for (int s = 0; s < 5; ++s) {
                const bf16x8 bf = *reinterpret_cast<const bf16x8*>(
                    &sB[cur][((f * 5 + s) * 64 + lane) * 8]);
                acc[0][f] = __builtin_amdgcn_mfma_f32_16x16x32_bf16(
                    afrag[0][s], bf, acc[0][f], 0, 0, 0);
                acc[1][f] = __builtin_amdgcn_mfma_f32_16x16x32_bf16(
                    afrag[1][s], bf, acc[1][f], 0, 0, 0);
            }
        }

        asm volatile("s_waitcnt vmcnt(0)" ::: "memory");
        __syncthreads();

        // ---- epilogue AFTER barrier: overlaps next iteration's compute.
        const int n0 = t * 64;
        #pragma unroll
        for (int f = 0; f < 4; ++f) {
            const int v  = n0 + f * 16 + r;
            const int vc = (v < VN_) ? v : VN_ - 1;
            const float3 p = *reinterpret_cast<const float3*>(vt + 3 * (size_t)vc);
            #pragma unroll
            for (int mi = 0; mi < 2; ++mi) {
                const f32x4 c = acc[mi][f];
                const float val = c[0] * p.x + c[1] * p.y + c[2] * p.z + c[3];
                const float xx = __shfl(val, r);
                const float yy = __shfl(val, 16 + r);
                const float zz = __shfl(val, 32 + r);
                if (lane < 16 && v < VN_) {
                    float* o = out + ((size_t)(batch0 + w * 2 + mi) * VN_ + v) * 3;
                    *reinterpret_cast<float3*>(o) = make_float3(xx, yy, zz);
                }
            }
        }
        cur ^= 1;
    }
}

// ---------------------------------------------------------------------------
// Kernel 3: keypoints.
// ---------------------------------------------------------------------------
__global__ __launch_bounds__(256) void kp_kernel(
    const int* __restrict__ kpv, const int* __restrict__ kpj,
    const int* __restrict__ kpb, float* __restrict__ out)
{
    const int i = blockIdx.x * 256 + threadIdx.x;
    if (i >= B_ * NKP) return;
    const int b  = i / NKP;
    const int kk = i - b * NKP;

    float vx, vy, vz;
    if (kpb[kk] != 0) {
        int j0 = kpj[kk * 2 + 0], j1 = kpj[kk * 2 + 1];
        if (j0 < 0 || j0 >= J_) j0 = 0;
        if (j1 < 0 || j1 >= J_) j1 = 0;
        const float* p0 = out + OFF_J + ((size_t)b * J_ + j0) * 3;
        const float* p1 = out + OFF_J + ((size_t)b * J_ + j1) * 3;
        vx = 0.5f * (p0[0] + p1[0]);
        vy = 0.5f * (p0[1] + p1[1]);
        vz = 0.5f * (p0[2] + p1[2]);
    } else {
        vx = vy = vz = 0.0f;
        #pragma unroll
        for (int q = 0; q < 4; ++q) {
            int vid = kpv[kk * 4 + q];
            if (vid < 0 || vid >= VN_) vid = 0;
            const float* p = out + ((size_t)b * VN_ + vid) * 3;
            vx += p[0]; vy += p[1]; vz += p[2];
        }
        vx *= 0.25f; vy *= 0.25f; vz *= 0.25f;
    }
    float* o = out + OFF_K + ((size_t)b * NKP + kk) * 3;
    o[0] = vx; o[1] = vy; o[2] = vz;
}

// ---------------------------------------------------------------------------
extern "C" void kernel_launch(void* const* d_in, const int* in_sizes, int n_in,
                              void* d_out, int out_size, void* d_ws, size_t ws_size,
                              hipStream_t stream) {
    const float* rotvec  = (const float*)d_in[0];
    const float* ptrans  = (const float*)d_in[1];
    const float* vt      = (const float*)d_in[2];
    const float* w       = (const float*)d_in[3];
    const float* tpose   = (const float*)d_in[4];
    const void*  parents = (const void*)d_in[5];
    const int*   kpv     = (const int*)d_in[6];
    const int*   kpj     = (const int*)d_in[7];
    const int*   kpb     = (const int*)d_in[8];

    float*  out = (float*)d_out;
    __bf16* Abf = (__bf16*)d_ws;                               // 1.31 MB
    __bf16* Wbf = (__bf16*)((char*)d_ws + (size_t)MP * KP * 2); // 4.48 MB

    prep_kernel<<<B_ + PREPW_BLOCKS, 256, 0, stream>>>(
        rotvec, ptrans, tpose, parents, w, Abf, Wbf, out + OFF_J);

    dim3 grid(NSPLIT, MP / 128);    // (32, 32) = 1024 blocks
    gemm_kernel<<<grid, 256, 0, stream>>>(Abf, Wbf, vt, out);

    kp_kernel<<<(B_ * NKP + 255) / 256, 256, 0, stream>>>(kpv, kpj, kpb, out);
}

// Round 7
// 39.669 us; speedup vs baseline: 6.7021x; 1.2644x over previous
//
#include <hip/hip_runtime.h>

#define B_   256
#define J_   140
#define VN_  14000
#define NKP  22
#define KP   160        // K padded to multiple of 32
#define MP   4096       // M = B*16
#define NSPLIT 32
#define NT   219        // ceil(VN/64) N-tiles of 64 vertices

#define OFF_J (B_ * VN_ * 3)
#define OFF_K (OFF_J + B_ * J_ * 3)

#define PREPW_BLOCKS ((VN_ * (KP / 8) + 255) / 256)

typedef __attribute__((ext_vector_type(8))) __bf16 bf16x8;
typedef __attribute__((ext_vector_type(4))) float  f32x4;
typedef unsigned int u32;

__device__ __forceinline__ void gload_lds16(const void* g, void* l) {
    __builtin_amdgcn_global_load_lds(
        (const __attribute__((address_space(1))) u32*)g,
        (__attribute__((address_space(3))) u32*)l, 16, 0, 0);
}

// ---------------------------------------------------------------------------
// Kernel 1 (fused): blocks [0,B_) = kinematic chain (barrier-free ancestor
// walk, 2 barriers total); blocks [B_, B_+PREPW_BLOCKS) = weights -> bf16.
// ---------------------------------------------------------------------------
__global__ __launch_bounds__(256) void prep_kernel(
    const float* __restrict__ rotvec,
    const float* __restrict__ ptrans,
    const float* __restrict__ tpose,
    const void*  __restrict__ parents_raw,
    const float* __restrict__ w,
    __bf16* __restrict__ Abf,
    __bf16* __restrict__ Wbf,
    float*  __restrict__ Jout)
{
    // ---------------- weights cast part ----------------
    if (blockIdx.x >= B_) {
        const int id = (blockIdx.x - B_) * 256 + threadIdx.x;
        if (id < VN_ * (KP / 8)) {
            const int v  = id / (KP / 8);
            const int jc = (id % (KP / 8)) * 8;
            __bf16 tmp[8];
            #pragma unroll
            for (int e = 0; e < 8; ++e) {
                const int j = jc + e;
                tmp[e] = (__bf16)((j < J_) ? w[(size_t)v * J_ + j] : 0.0f);
            }
            *reinterpret_cast<int4*>(Wbf + (size_t)v * KP + jc) =
                *reinterpret_cast<int4*>(tmp);
        }
        return;
    }

    // ---------------- chain part ----------------
    __shared__ float sS[J_][12];
    __shared__ float sA[J_][12];
    __shared__ int   sPar[J_];

    const int b = blockIdx.x;
    const int t = threadIdx.x;

    const int* p32 = (const int*)parents_raw;
    bool is64 = true;
    for (int k = 0; k < J_ / 2; ++k)
        if (p32[2 * k + 1] != 0) { is64 = false; break; }

    if (t < J_) {
        const int j = t;
        int p = is64 ? p32[2 * j] : p32[j];
        if (j == 0 || p < 0 || p >= j) p = 0;
        sPar[j] = p;

        const size_t base = ((size_t)b * J_ + j) * 3;
        const float rx = rotvec[base + 0], ry = rotvec[base + 1], rz = rotvec[base + 2];
        const float th  = sqrtf(rx * rx + ry * ry + rz * rz) + 1e-8f;
        const float inv = 1.0f / th;
        const float ux = rx * inv, uy = ry * inv, uz = rz * inv;
        const float c = cosf(th), s = sinf(th);
        const float omc = 1.0f - c;

        sS[j][0]  = c + omc * ux * ux;
        sS[j][1]  = omc * ux * uy - s * uz;
        sS[j][2]  = omc * ux * uz + s * uy;
        sS[j][4]  = omc * uy * ux + s * uz;
        sS[j][5]  = c + omc * uy * uy;
        sS[j][6]  = omc * uy * uz - s * ux;
        sS[j][8]  = omc * uz * ux - s * uy;
        sS[j][9]  = omc * uz * uy + s * ux;
        sS[j][10] = c + omc * uz * uz;
        sS[j][3]  = ptrans[base + 0];
        sS[j][7]  = ptrans[base + 1];
        sS[j][11] = ptrans[base + 2];
    }
    __syncthreads();

    if (t < J_) {
        const int j = t;
        // G = S[j]; walk up: G = S[p] @ G (affine compose), no barriers.
        float g[12];
        #pragma unroll
        for (int q = 0; q < 12; ++q) g[q] = sS[j][q];

        int cur = j;
        for (int it = 0; it < J_ && cur != 0; ++it) {
            const int p = sPar[cur];
            float ng[12];
            #pragma unroll
            for (int m = 0; m < 3; ++m) {
                const float s0 = sS[p][m*4+0], s1 = sS[p][m*4+1];
                const float s2 = sS[p][m*4+2], s3 = sS[p][m*4+3];
                #pragma unroll
                for (int cc = 0; cc < 4; ++cc)
                    ng[m*4+cc] = s0 * g[0*4+cc] + s1 * g[1*4+cc] + s2 * g[2*4+cc]
                               + ((cc == 3) ? s3 : 0.0f);
            }
            #pragma unroll
            for (int q = 0; q < 12; ++q) g[q] = ng[q];
            cur = p;
        }

        // A = [R | t - R*tpose]; J_final = t
        const float tx = tpose[j*3+0], ty = tpose[j*3+1], tz = tpose[j*3+2];
        #pragma unroll
        for (int m = 0; m < 3; ++m) {
            const float r0 = g[m*4+0], r1 = g[m*4+1], r2 = g[m*4+2];
            const float gt = g[m*4+3];
            sA[j][m*4+0] = r0;
            sA[j][m*4+1] = r1;
            sA[j][m*4+2] = r2;
            sA[j][m*4+3] = gt - (r0 * tx + r1 * ty + r2 * tz);
            Jout[((size_t)b * J_ + j) * 3 + m] = gt;
        }
    }
    __syncthreads();

    // coalesced bf16 A write: comp-major [16][KP]
    for (int idx = t; idx < 16 * KP; idx += 256) {
        const int comp = idx / KP, j = idx % KP;
        const float val = (comp < 12 && j < J_) ? sA[j][comp] : 0.0f;
        Abf[((size_t)b * 16 + comp) * KP + j] = (__bf16)val;
    }
}

// ---------------------------------------------------------------------------
// Kernel 2: GEMM + fused LBS epilogue. Block = 4 waves, wave owns 4 batches
// (M=64 rows), block M=256 rows; 80 MFMA per 20 ds_read_b128 per iter.
// B double-buffered via global_load_lds, fragment-order (conflict-free).
// Epilogue: LDS-transpose (stride-5 floats, conflict-free) -> dense
// dwordx3 stores, no shfl.
// ---------------------------------------------------------------------------
__global__ __launch_bounds__(256, 2) void gemm_kernel(
    const __bf16* __restrict__ Abf,   // (MP, KP)
    const __bf16* __restrict__ Wbf,   // (VN, KP)
    const float*  __restrict__ vt,    // (VN, 3)
    float* __restrict__ out)          // (B, VN, 3)
{
    __shared__ __bf16 sB[2][4 * 5 * 64 * 8];    // 2 x 20 KB
    __shared__ float  sE[4][4][64 * 5];         // 20 KB epilogue scratch

    const int lane = threadIdx.x & 63;
    const int w    = threadIdx.x >> 6;
    const int r    = lane & 15;
    const int q    = lane >> 4;
    const int q16  = q * 16;                    // byte offset of k-quad
    const int batch0 = blockIdx.y * 16;
    const int row0   = blockIdx.y * 256;

    // ---- A fragments straight from global (L2-hot): 4 x 5 x 16B per lane
    bf16x8 afrag[4][5];
    #pragma unroll
    for (int mi = 0; mi < 4; ++mi) {
        const char* g = (const char*)(Abf + (size_t)(row0 + (w * 4 + mi) * 16 + r) * KP) + q16;
        #pragma unroll
        for (int s = 0; s < 5; ++s)
            afrag[mi][s] = *reinterpret_cast<const bf16x8*>(g + s * 64);
    }

    // ---- stage B tile 0: wave w stages frag f = w
    {
        int v = blockIdx.x * 64 + w * 16 + r;
        if (v >= VN_) v = VN_ - 1;
        const char* g = (const char*)(Wbf + (size_t)v * KP) + q16;
        char* lb = (char*)&sB[0][0] + w * 5 * 1024;
        #pragma unroll
        for (int s = 0; s < 5; ++s)
            gload_lds16(g + s * 64, lb + s * 1024);
    }
    asm volatile("s_waitcnt vmcnt(0)" ::: "memory");
    __syncthreads();

    int cur = 0;
    for (int t = blockIdx.x; t < NT; t += NSPLIT) {
        // ---- prefetch next B tile into other buffer (async)
        const int tn = t + NSPLIT;
        if (tn < NT) {
            int v = tn * 64 + w * 16 + r;
            if (v >= VN_) v = VN_ - 1;
            const char* g = (const char*)(Wbf + (size_t)v * KP) + q16;
            char* lb = (char*)&sB[cur ^ 1][0] + w * 5 * 1024;
            #pragma unroll
            for (int s = 0; s < 5; ++s)
                gload_lds16(g + s * 64, lb + s * 1024);
        }

        // ---- compute: 80 MFMA per wave from sB[cur]
        f32x4 acc[4][4];
        #pragma unroll
        for (int mi = 0; mi < 4; ++mi)
            #pragma unroll
            for (int f = 0; f < 4; ++f)
                acc[mi][f] = (f32x4){0.f, 0.f, 0.f, 0.f};

        #pragma unroll
        for (int f = 0; f < 4; ++f) {
            #pragma unroll
            for (int s = 0; s < 5; ++s) {
                const bf16x8 bf = *reinterpret_cast<const bf16x8*>(
                    &sB[cur][((f * 5 + s) * 64 + lane) * 8]);
                #pragma unroll
                for (int mi = 0; mi < 4; ++mi)
                    acc[mi][f] = __builtin_amdgcn_mfma_f32_16x16x32_bf16(
                        afrag[mi][s], bf, acc[mi][f], 0, 0, 0);
            }
        }

        asm volatile("s_waitcnt vmcnt(0)" ::: "memory");
        __syncthreads();

        // ---- epilogue (after barrier; same-wave LDS scratch, no sync).
        const int n0 = t * 64;
        #pragma unroll
        for (int f = 0; f < 4; ++f) {
            const int v  = n0 + f * 16 + r;
            const int vc = (v < VN_) ? v : VN_ - 1;
            const float3 p = *reinterpret_cast<const float3*>(vt + 3 * (size_t)vc);
            if (q < 3) {
                #pragma unroll
                for (int mi = 0; mi < 4; ++mi) {
                    const f32x4 c = acc[mi][f];
                    const float val = c[0] * p.x + c[1] * p.y + c[2] * p.z + c[3];
                    sE[w][mi][(f * 16 + r) * 5 + q] = val;
                }
            }
        }
        // dense stores: lane L -> vertex n0+L, 12B each, 768B/instr
        const int vst = n0 + lane;
        if (vst < VN_) {
            #pragma unroll
            for (int mi = 0; mi < 4; ++mi) {
                const float x = sE[w][mi][lane * 5 + 0];
                const float y = sE[w][mi][lane * 5 + 1];
                const float z = sE[w][mi][lane * 5 + 2];
                float* o = out + ((size_t)(batch0 + w * 4 + mi) * VN_ + vst) * 3;
                o[0] = x; o[1] = y; o[2] = z;
            }
        }
        cur ^= 1;
    }
}

// ---------------------------------------------------------------------------
// Kernel 3: keypoints.
// ---------------------------------------------------------------------------
__global__ __launch_bounds__(256) void kp_kernel(
    const int* __restrict__ kpv, const int* __restrict__ kpj,
    const int* __restrict__ kpb, float* __restrict__ out)
{
    const int i = blockIdx.x * 256 + threadIdx.x;
    if (i >= B_ * NKP) return;
    const int b  = i / NKP;
    const int kk = i - b * NKP;

    float vx, vy, vz;
    if (kpb[kk] != 0) {
        int j0 = kpj[kk * 2 + 0], j1 = kpj[kk * 2 + 1];
        if (j0 < 0 || j0 >= J_) j0 = 0;
        if (j1 < 0 || j1 >= J_) j1 = 0;
        const float* p0 = out + OFF_J + ((size_t)b * J_ + j0) * 3;
        const float* p1 = out + OFF_J + ((size_t)b * J_ + j1) * 3;
        vx = 0.5f * (p0[0] + p1[0]);
        vy = 0.5f * (p0[1] + p1[1]);
        vz = 0.5f * (p0[2] + p1[2]);
    } else {
        vx = vy = vz = 0.0f;
        #pragma unroll
        for (int qq = 0; qq < 4; ++qq) {
            int vid = kpv[kk * 4 + qq];
            if (vid < 0 || vid >= VN_) vid = 0;
            const float* p = out + ((size_t)b * VN_ + vid) * 3;
            vx += p[0]; vy += p[1]; vz += p[2];
        }
        vx *= 0.25f; vy *= 0.25f; vz *= 0.25f;
    }
    float* o = out + OFF_K + ((size_t)b * NKP + kk) * 3;
    o[0] = vx; o[1] = vy; o[2] = vz;
}

// ---------------------------------------------------------------------------
extern "C" void kernel_launch(void* const* d_in, const int* in_sizes, int n_in,
                              void* d_out, int out_size, void* d_ws, size_t ws_size,
                              hipStream_t stream) {
    const float* rotvec  = (const float*)d_in[0];
    const float* ptrans  = (const float*)d_in[1];
    const float* vt      = (const float*)d_in[2];
    const float* w       = (const float*)d_in[3];
    const float* tpose   = (const float*)d_in[4];
    const void*  parents = (const void*)d_in[5];
    const int*   kpv     = (const int*)d_in[6];
    const int*   kpj     = (const int*)d_in[7];
    const int*   kpb     = (const int*)d_in[8];

    float*  out = (float*)d_out;
    __bf16* Abf = (__bf16*)d_ws;                               // 1.31 MB
    __bf16* Wbf = (__bf16*)((char*)d_ws + (size_t)MP * KP * 2); // 4.48 MB

    prep_kernel<<<B_ + PREPW_BLOCKS, 256, 0, stream>>>(
        rotvec, ptrans, tpose, parents, w, Abf, Wbf, out + OFF_J);

    dim3 grid(NSPLIT, MP / 256);    // (32, 16) = 512 blocks
    gemm_kernel<<<grid, 256, 0, stream>>>(Abf, Wbf, vt, out);

    kp_kernel<<<(B_ * NKP + 255) / 256, 256, 0, stream>>>(kpv, kpj, kpb, out);
}